// Round 1
// baseline (102.466 us; speedup 1.0000x reference)
//
#include <hip/hip_runtime.h>

// DynamicPatcher: outputs are (patch_lengths (B,P) int32, patch_ids (B,S) int32),
// concatenated flat in d_out. Input entropy is used only for its SHAPE, never
// its values -> no global reads needed. Pure store kernel, memory-bound on
// ~67 MB of int32 writes.
//
// Closed form of the reference fill loop (host-side, depends only on S,P):
//   avg = max(S/P, 1)
//   nf  = number of leading patches filled with avg
//   if break happened (nf < P-1): lengths[nf] = S - nf*avg, lengths[P-1] = same
//   else: lengths[P-1] = S - (P-1)*avg  (always > 0 in that branch)
// patch_ids[pos] = right-searchsorted(cumsum, pos) = min(pos/avg, nf).

__global__ __launch_bounds__(256) void DynamicPatcher_62448824484363_kernel(
    int* __restrict__ out,
    int BP,        // B*P  (start offset of patch_ids region), multiple of 4
    int total,     // out_size, multiple of 4
    int S,         // seq len, multiple of 4
    int P,         // MAX_PATCHES (1024), multiple of 4
    int avg,
    int nf,
    int breakRem,
    int lastVal)
{
    int t = blockIdx.x * 256 + threadIdx.x;
    int i = t * 4;                      // first element this thread writes
    if (i >= total) return;

    int4 v;
    if (i < BP) {
        // ---- patch_lengths region ----
        // P % 4 == 0 and i % 4 == 0, so the 4 lanes stay inside one row.
        int p0 = i % P;
        #define LVAL(p) ((p) < nf ? avg : ((p) == P - 1 ? lastVal : ((p) == nf ? breakRem : 0)))
        v.x = LVAL(p0);
        v.y = LVAL(p0 + 1);
        v.z = LVAL(p0 + 2);
        v.w = LVAL(p0 + 3);
        #undef LVAL
    } else {
        // ---- patch_ids region ----
        int e = i - BP;
        int pos0 = e % S;               // S % 4 == 0 -> 4 positions in one row
        int q = pos0 / avg;
        int r = pos0 - q * avg;         // 0 <= r < avg
        int a2 = avg + avg;
        int a3 = a2 + avg;
        // (r+k)/avg for k<=3 is 0..3; valid for any avg >= 1.
        v.x = min(q, nf);
        v.y = min(q + (r + 1 >= avg) + (r + 1 >= a2) + (r + 1 >= a3), nf);
        v.z = min(q + (r + 2 >= avg) + (r + 2 >= a2) + (r + 2 >= a3), nf);
        v.w = min(q + (r + 3 >= avg) + (r + 3 >= a2) + (r + 3 >= a3), nf);
    }
    *reinterpret_cast<int4*>(out + i) = v;   // 16 B coalesced store
}

extern "C" void kernel_launch(void* const* d_in, const int* in_sizes, int n_in,
                              void* d_out, int out_size, void* d_ws, size_t ws_size,
                              hipStream_t stream) {
    (void)d_in; (void)n_in; (void)d_ws; (void)ws_size;

    const int P = 1024;                         // MAX_PATCHES
    long long BS = (long long)in_sizes[0];      // B*S  (entropy element count)
    long long BPll = (long long)out_size - BS;  // B*P
    long long B = BPll / P;
    long long S = BS / B;

    long long avgll = S / P;
    if (avgll < 1) avgll = 1;
    int avg = (int)avgll;

    // nf = #iterations p in [0, P-1) with remaining (= S - p*avg) > avg
    long long nfll = 0;
    if (S > avg) {
        nfll = (S - avg - 1) / avg + 1;
        if (nfll > P - 1) nfll = P - 1;
    }
    int nf = (int)nfll;

    int breakRem = (int)(S - nfll * avg);       // remaining at break (if any)
    int lastVal;
    if (nf < P - 1) {
        lastVal = breakRem;                     // break leaves 'remaining' unchanged
    } else {
        long long rf = S - (long long)(P - 1) * avg;
        lastVal = rf > 0 ? (int)rf : 0;
    }

    int total = out_size;                       // 16,793,600 here (multiple of 4)
    int threads = total / 4;
    int blocks = (threads + 255) / 256;

    DynamicPatcher_62448824484363_kernel<<<blocks, 256, 0, stream>>>(
        (int*)d_out, (int)BPll, total, (int)S, P, avg, nf, breakRem, lastVal);
}

// Round 2
// 101.492 us; speedup vs baseline: 1.0096x; 1.0096x over previous
//
#include <hip/hip_runtime.h>

// DynamicPatcher: out = [patch_lengths (B,P) int32 | patch_ids (B,S) int32] flat.
// Input entropy is used only for its shape -> pure store kernel, ~67 MB writes.
//
// Closed form (host-side): avg = max(S/P,1); nf = #leading patches of size avg;
// lengths[p<nf]=avg, lengths[nf]=breakRem (if break), lengths[P-1]=lastVal;
// patch_ids[pos] = min(pos/avg, nf).
//
// Layout: gridDim.y = row (batch). x-blocks [0, blocksPerRow) write patch_ids
// (each thread: 4 x int4 = 64 B, fully coalesced). x-block == blocksPerRow
// writes the row's patch_lengths. avg pow2 -> shift; else u32 div fallback.

template <bool POW2>
__global__ __launch_bounds__(256) void DynamicPatcher_62448824484363_kernel(
    int* __restrict__ out,
    int B, int S, int P,
    int avg, int sh,           // sh = log2(avg) when POW2
    int nf, int breakRem, int lastVal,
    int blocksPerRow)
{
    const int row = blockIdx.y;

    if ((int)blockIdx.x == blocksPerRow) {
        // ---- patch_lengths for this row ----
        int* lrow = out + (size_t)row * P;
        for (int i = threadIdx.x * 4; i < P; i += 256 * 4) {
            int4 v;
            #define LVAL(p) ((p) < nf ? avg : ((p) == P - 1 ? lastVal : ((p) == nf ? breakRem : 0)))
            v.x = LVAL(i);
            v.y = LVAL(i + 1);
            v.z = LVAL(i + 2);
            v.w = LVAL(i + 3);
            #undef LVAL
            *reinterpret_cast<int4*>(lrow + i) = v;
        }
        return;
    }

    // ---- patch_ids for this row ----
    int* irow = out + (size_t)B * P + (size_t)row * S;
    const int base = blockIdx.x * 4096 + threadIdx.x * 4;  // element index

    #pragma unroll
    for (int u = 0; u < 4; ++u) {
        int pos = base + u * 1024;
        if (pos >= S) break;           // only the ragged last block ever exits here
        int4 v;
        if (POW2) {
            v.x = min(pos >> sh, nf);
            v.y = min((pos + 1) >> sh, nf);
            v.z = min((pos + 2) >> sh, nf);
            v.w = min((pos + 3) >> sh, nf);
        } else {
            int q = pos / avg;         // wave-uniform-divisor u32 div (rare path)
            int r = pos - q * avg;
            int a2 = avg + avg;
            int a3 = a2 + avg;
            v.x = min(q, nf);
            v.y = min(q + (r + 1 >= avg) + (r + 1 >= a2) + (r + 1 >= a3), nf);
            v.z = min(q + (r + 2 >= avg) + (r + 2 >= a2) + (r + 2 >= a3), nf);
            v.w = min(q + (r + 3 >= avg) + (r + 3 >= a2) + (r + 3 >= a3), nf);
        }
        *reinterpret_cast<int4*>(irow + pos) = v;  // 16 B coalesced store
    }
}

extern "C" void kernel_launch(void* const* d_in, const int* in_sizes, int n_in,
                              void* d_out, int out_size, void* d_ws, size_t ws_size,
                              hipStream_t stream) {
    (void)d_in; (void)n_in; (void)d_ws; (void)ws_size;

    const int P = 1024;                          // MAX_PATCHES
    long long BS = (long long)in_sizes[0];       // B*S
    long long BPll = (long long)out_size - BS;   // B*P
    int B = (int)(BPll / P);
    int S = (int)(BS / B);

    long long avgll = (long long)S / P;
    if (avgll < 1) avgll = 1;
    int avg = (int)avgll;

    // nf = #iterations p in [0, P-1) with remaining (= S - p*avg) > avg
    long long nfll = 0;
    if (S > avg) {
        nfll = ((long long)S - avg - 1) / avg + 1;
        if (nfll > P - 1) nfll = P - 1;
    }
    int nf = (int)nfll;

    int breakRem = (int)(S - nfll * avg);
    int lastVal;
    if (nf < P - 1) {
        lastVal = breakRem;                      // break leaves 'remaining' unchanged
    } else {
        long long rf = (long long)S - (long long)(P - 1) * avg;
        lastVal = rf > 0 ? (int)rf : 0;
    }

    int blocksPerRow = (S + 4095) / 4096;        // 4096 elements per x-block
    dim3 grid(blocksPerRow + 1, B);

    bool pow2 = (avg & (avg - 1)) == 0;
    int sh = 0;
    if (pow2) { int a = avg; while (a > 1) { a >>= 1; ++sh; } }

    if (pow2) {
        DynamicPatcher_62448824484363_kernel<true><<<grid, 256, 0, stream>>>(
            (int*)d_out, B, S, P, avg, sh, nf, breakRem, lastVal, blocksPerRow);
    } else {
        DynamicPatcher_62448824484363_kernel<false><<<grid, 256, 0, stream>>>(
            (int*)d_out, B, S, P, avg, sh, nf, breakRem, lastVal, blocksPerRow);
    }
}